// Round 3
// baseline (135.639 us; speedup 1.0000x reference)
//
#include <hip/hip_runtime.h>

#define TPB    256
#define CHUNKS 16     // blocks per batch along T -> 2048 blocks = 8/CU = 32 waves/CU
#define NACC   21     // 16 D[i][j] + 4 S1[i] + 1 denom
#define NPERM  24

__constant__ int c_perm[NPERM][4] = {
    {0,1,2,3},{0,1,3,2},{0,2,1,3},{0,2,3,1},{0,3,1,2},{0,3,2,1},
    {1,0,2,3},{1,0,3,2},{1,2,0,3},{1,2,3,0},{1,3,0,2},{1,3,2,0},
    {2,0,1,3},{2,0,3,1},{2,1,0,3},{2,1,3,0},{2,3,0,1},{2,3,1,0},
    {3,0,1,2},{3,0,2,1},{3,1,0,2},{3,1,2,0},{3,2,0,1},{3,2,1,0}
};

// bce[b,t,i,j] = -lq_i + t_j*(lq_i - lp_i); accumulate
//   D[i][j] = sum_t m * t_j * (lq_i - lp_i)
//   S1[i]   = sum_t m * lq_i
//   dn      = sum_t m
__device__ __forceinline__ void accum_row(const float4 pv, const float4 tv, const float m,
                                          float (&D)[4][4], float (&S1)[4], float& dn)
{
    const float lo = 1e-7f;
    const float hi = 1.0f - 1e-7f;
    float pp[4] = {pv.x, pv.y, pv.z, pv.w};
    float tt[4] = {tv.x, tv.y, tv.z, tv.w};
    float lp[4], lq[4];
    #pragma unroll
    for (int s = 0; s < 4; ++s) {
        float p = fminf(fmaxf(pp[s], lo), hi);
        lp[s] = __logf(p);
        lq[s] = __logf(1.0f - p);
    }
    dn += m;
    float mt[4];
    #pragma unroll
    for (int j = 0; j < 4; ++j) mt[j] = m * tt[j];
    #pragma unroll
    for (int i = 0; i < 4; ++i) {
        S1[i] = fmaf(m, lq[i], S1[i]);
        float d = lq[i] - lp[i];
        #pragma unroll
        for (int j = 0; j < 4; ++j) D[i][j] = fmaf(d, mt[j], D[i][j]);
    }
}

// Stage 1: per-(batch, T-chunk) partial sums of the 21 accumulators.
// Bit-identical to round 2.
__global__ __launch_bounds__(TPB) void pit_partial(
    const float* __restrict__ pred, const float* __restrict__ target,
    const float* __restrict__ mask, float* __restrict__ partial, int T)
{
    const int b      = blockIdx.x / CHUNKS;
    const int chunk  = blockIdx.x - b * CHUNKS;
    const int tPerBlock = (T + CHUNKS - 1) / CHUNKS;   // 1024 for T=16384
    const int tid    = threadIdx.x;
    const int base   = chunk * tPerBlock;
    const int tEnd   = min(base + tPerBlock, T);

    const float4* p4  = (const float4*)pred   + (size_t)b * T;
    const float4* t4  = (const float4*)target + (size_t)b * T;
    const float* mrow = mask + (size_t)b * T;

    float D[4][4] = {{0.f,0.f,0.f,0.f},{0.f,0.f,0.f,0.f},
                     {0.f,0.f,0.f,0.f},{0.f,0.f,0.f,0.f}};
    float S1[4] = {0.f,0.f,0.f,0.f};
    float dn = 0.f;

    int t0 = base + tid;
    if (t0 + 3 * TPB < tEnd) {
        float4 pv[4], tv[4];
        float  mv[4];
        #pragma unroll
        for (int r = 0; r < 4; ++r) pv[r] = p4[t0 + r * TPB];
        #pragma unroll
        for (int r = 0; r < 4; ++r) tv[r] = t4[t0 + r * TPB];
        #pragma unroll
        for (int r = 0; r < 4; ++r) mv[r] = mrow[t0 + r * TPB];
        #pragma unroll
        for (int r = 0; r < 4; ++r)
            accum_row(pv[r], tv[r], mv[r], D, S1, dn);
        t0 += 4 * TPB;
    }
    for (; t0 < tEnd; t0 += TPB)        // generic-T tail (empty for T=16384)
        accum_row(p4[t0], t4[t0], mrow[t0], D, S1, dn);

    float acc[NACC];
    #pragma unroll
    for (int i = 0; i < 4; ++i)
        #pragma unroll
        for (int j = 0; j < 4; ++j) acc[i * 4 + j] = D[i][j];
    #pragma unroll
    for (int i = 0; i < 4; ++i) acc[16 + i] = S1[i];
    acc[20] = dn;

    #pragma unroll
    for (int k = 0; k < NACC; ++k) {
        float v = acc[k];
        #pragma unroll
        for (int off = 32; off > 0; off >>= 1)
            v += __shfl_xor(v, off, 64);
        acc[k] = v;
    }

    __shared__ float sred[TPB / 64][NACC];
    const int wave = tid >> 6;
    const int lane = tid & 63;
    if (lane == 0) {
        #pragma unroll
        for (int k = 0; k < NACC; ++k) sred[wave][k] = acc[k];
    }
    __syncthreads();
    if (tid < NACC) {
        float v = 0.f;
        #pragma unroll
        for (int w = 0; w < TPB / 64; ++w) v += sred[w][tid];
        partial[(size_t)tid * gridDim.x + blockIdx.x] = v;
    }
}

// Stage 2: identical to round 2.
__global__ __launch_bounds__(256) void pit_final(
    const float* __restrict__ partial, float* __restrict__ out, int B, int nblk)
{
    const int tid = threadIdx.x;
    float sumMin = 0.f;

    for (int bb = tid; bb < B; bb += blockDim.x) {
        float A[NACC];
        #pragma unroll
        for (int k = 0; k < NACC; ++k) {
            const float* src = partial + (size_t)k * nblk + bb * CHUNKS;
            float v = 0.f;
            #pragma unroll
            for (int c = 0; c < CHUNKS; ++c) v += src[c];
            A[k] = v;
        }
        const float inv = 1.0f / (4.0f * A[20]);   // 1/(S*denom)
        float C[4][4];
        #pragma unroll
        for (int i = 0; i < 4; ++i)
            #pragma unroll
            for (int j = 0; j < 4; ++j)
                C[i][j] = (A[i * 4 + j] - A[16 + i]) * inv;

        float minv = 3.4e38f;
        int mini = 0;
        #pragma unroll
        for (int p = 0; p < NPERM; ++p) {
            float v = C[0][c_perm[p][0]] + C[1][c_perm[p][1]]
                    + C[2][c_perm[p][2]] + C[3][c_perm[p][3]];
            if (v < minv) { minv = v; mini = p; }   // strict <: first-occurrence argmin
        }
        #pragma unroll
        for (int i = 0; i < 4; ++i)
            out[1 + bb * 4 + i] = (float)c_perm[mini][i];
        sumMin += minv;
    }

    float v = sumMin;
    #pragma unroll
    for (int off = 32; off > 0; off >>= 1)
        v += __shfl_xor(v, off, 64);
    __shared__ float ssum[4];
    const int wave = tid >> 6;
    if ((tid & 63) == 0) ssum[wave] = v;
    __syncthreads();
    if (tid == 0) {
        float s = 0.f;
        #pragma unroll
        for (int w = 0; w < 4; ++w) s += ssum[w];
        out[0] = s / (float)B;
    }
}

extern "C" void kernel_launch(void* const* d_in, const int* in_sizes, int n_in,
                              void* d_out, int out_size, void* d_ws, size_t ws_size,
                              hipStream_t stream)
{
    const float* pred   = (const float*)d_in[0];
    const float* target = (const float*)d_in[1];
    const float* mask   = (const float*)d_in[2];
    float* out      = (float*)d_out;
    float* partialA = (float*)d_ws;                       // NACC*(B*CHUNKS) floats = 172 KB
    float* partialB = (float*)((char*)d_ws + (4 << 20));  // disjoint region, result unused

    const int B = (out_size - 1) / 4;      // out = [loss] + [B,4] perms
    const int T = in_sizes[2] / B;         // mask is [B,T]
    const int nblk = B * CHUNKS;

    // DIAGNOSTIC ROUND: pit_partial dispatched twice (B-copy's output dead).
    // dur_us(this) - dur_us(round2) ~= partial_dur + node gap, resolving
    // whether stage 1 is ~40us (kernel prize remains) or ~15us (at floor).
    pit_partial<<<nblk, TPB, 0, stream>>>(pred, target, mask, partialB, T);
    pit_partial<<<nblk, TPB, 0, stream>>>(pred, target, mask, partialA, T);
    pit_final<<<1, 256, 0, stream>>>(partialA, out, B, nblk);
}

// Round 4
// 113.450 us; speedup vs baseline: 1.1956x; 1.1956x over previous
//
#include <hip/hip_runtime.h>

#define TPB    256
#define CHUNKS 8      // blocks per batch along T -> 1024 blocks; 8 rows/thread
#define NACC   21     // 16 D[i][j] + 4 S1[i] + 1 denom
#define NPERM  24

__constant__ int c_perm[NPERM][4] = {
    {0,1,2,3},{0,1,3,2},{0,2,1,3},{0,2,3,1},{0,3,1,2},{0,3,2,1},
    {1,0,2,3},{1,0,3,2},{1,2,0,3},{1,2,3,0},{1,3,0,2},{1,3,2,0},
    {2,0,1,3},{2,0,3,1},{2,1,0,3},{2,1,3,0},{2,3,0,1},{2,3,1,0},
    {3,0,1,2},{3,0,2,1},{3,1,0,2},{3,1,2,0},{3,2,0,1},{3,2,1,0}
};

// bce[b,t,i,j] = -lq_i + t_j*(lq_i - lp_i); accumulate
//   D[i][j] = sum_t m * t_j * (lq_i - lp_i)
//   S1[i]   = sum_t m * lq_i
//   dn      = sum_t m
__device__ __forceinline__ void accum_row(const float4 pv, const float4 tv, const float m,
                                          float (&D)[4][4], float (&S1)[4], float& dn)
{
    const float lo = 1e-7f;
    const float hi = 1.0f - 1e-7f;
    float pp[4] = {pv.x, pv.y, pv.z, pv.w};
    float tt[4] = {tv.x, tv.y, tv.z, tv.w};
    float lp[4], lq[4];
    #pragma unroll
    for (int s = 0; s < 4; ++s) {
        float p = fminf(fmaxf(pp[s], lo), hi);
        lp[s] = __logf(p);
        lq[s] = __logf(1.0f - p);
    }
    dn += m;
    float mt[4];
    #pragma unroll
    for (int j = 0; j < 4; ++j) mt[j] = m * tt[j];
    #pragma unroll
    for (int i = 0; i < 4; ++i) {
        S1[i] = fmaf(m, lq[i], S1[i]);
        float d = lq[i] - lp[i];
        #pragma unroll
        for (int j = 0; j < 4; ++j) D[i][j] = fmaf(d, mt[j], D[i][j]);
    }
}

// Stage 1: per-(batch, T-chunk) partial sums of the 21 accumulators.
// 8 rows/thread (2 x 4-row macro steps): amortizes the fixed ~270-instr
// butterfly epilogue over 2x the bytes vs CHUNKS=16, while keeping 12
// coalesced loads (144 B/lane) in flight per macro step.
// Per-thread row order ascending -> sums bit-identical to prior rounds.
__global__ __launch_bounds__(TPB) void pit_partial(
    const float* __restrict__ pred, const float* __restrict__ target,
    const float* __restrict__ mask, float* __restrict__ partial, int T)
{
    const int b      = blockIdx.x / CHUNKS;
    const int chunk  = blockIdx.x - b * CHUNKS;
    const int tPerBlock = (T + CHUNKS - 1) / CHUNKS;   // 2048 for T=16384
    const int tid    = threadIdx.x;
    const int base   = chunk * tPerBlock;
    const int tEnd   = min(base + tPerBlock, T);

    const float4* p4  = (const float4*)pred   + (size_t)b * T;
    const float4* t4  = (const float4*)target + (size_t)b * T;
    const float* mrow = mask + (size_t)b * T;

    float D[4][4] = {{0.f,0.f,0.f,0.f},{0.f,0.f,0.f,0.f},
                     {0.f,0.f,0.f,0.f},{0.f,0.f,0.f,0.f}};
    float S1[4] = {0.f,0.f,0.f,0.f};
    float dn = 0.f;

    int t0 = base + tid;
    for (; t0 + 3 * TPB < tEnd; t0 += 4 * TPB) {
        float4 pv[4], tv[4];
        float  mv[4];
        #pragma unroll
        for (int r = 0; r < 4; ++r) pv[r] = p4[t0 + r * TPB];
        #pragma unroll
        for (int r = 0; r < 4; ++r) tv[r] = t4[t0 + r * TPB];
        #pragma unroll
        for (int r = 0; r < 4; ++r) mv[r] = mrow[t0 + r * TPB];
        #pragma unroll
        for (int r = 0; r < 4; ++r)
            accum_row(pv[r], tv[r], mv[r], D, S1, dn);
    }
    for (; t0 < tEnd; t0 += TPB)        // generic-T tail (empty for T=16384)
        accum_row(p4[t0], t4[t0], mrow[t0], D, S1, dn);

    float acc[NACC];
    #pragma unroll
    for (int i = 0; i < 4; ++i)
        #pragma unroll
        for (int j = 0; j < 4; ++j) acc[i * 4 + j] = D[i][j];
    #pragma unroll
    for (int i = 0; i < 4; ++i) acc[16 + i] = S1[i];
    acc[20] = dn;

    // wave-64 butterfly reduction for each accumulator
    #pragma unroll
    for (int k = 0; k < NACC; ++k) {
        float v = acc[k];
        #pragma unroll
        for (int off = 32; off > 0; off >>= 1)
            v += __shfl_xor(v, off, 64);
        acc[k] = v;
    }

    __shared__ float sred[TPB / 64][NACC];
    const int wave = tid >> 6;
    const int lane = tid & 63;
    if (lane == 0) {
        #pragma unroll
        for (int k = 0; k < NACC; ++k) sred[wave][k] = acc[k];
    }
    __syncthreads();
    // Transposed layout: partial[k][blockIdx] so stage 2 reads contiguous runs.
    if (tid < NACC) {
        float v = 0.f;
        #pragma unroll
        for (int w = 0; w < TPB / 64; ++w) v += sred[w][tid];
        partial[(size_t)tid * gridDim.x + blockIdx.x] = v;
    }
}

// Stage 2: one block; thread bb sums its 8 chunk-partials (two float4 loads
// in the transposed layout, sequential adds keep the reduction order),
// builds C[4][4], scans the 24 permutations (strict < keeps argmin's
// first-occurrence rule), block-reduces the mean loss.
__global__ __launch_bounds__(128) void pit_final(
    const float* __restrict__ partial, float* __restrict__ out, int B, int nblk)
{
    const int b = threadIdx.x;
    float minv = 0.f;

    if (b < B) {
        float A[NACC];
        #pragma unroll
        for (int k = 0; k < NACC; ++k) {
            const float4* src4 =
                (const float4*)(partial + (size_t)k * nblk + b * CHUNKS);
            float4 x = src4[0];
            float4 y = src4[1];
            float v = x.x;
            v += x.y; v += x.z; v += x.w;
            v += y.x; v += y.y; v += y.z; v += y.w;
            A[k] = v;
        }
        const float inv = 1.0f / (4.0f * A[20]);   // 1/(S*denom)
        float C[4][4];
        #pragma unroll
        for (int i = 0; i < 4; ++i)
            #pragma unroll
            for (int j = 0; j < 4; ++j)
                C[i][j] = (A[i * 4 + j] - A[16 + i]) * inv;

        minv = 3.4e38f;
        int mini = 0;
        #pragma unroll
        for (int p = 0; p < NPERM; ++p) {
            float v = C[0][c_perm[p][0]] + C[1][c_perm[p][1]]
                    + C[2][c_perm[p][2]] + C[3][c_perm[p][3]];
            if (v < minv) { minv = v; mini = p; }   // strict <: first-occurrence argmin
        }
        #pragma unroll
        for (int i = 0; i < 4; ++i)
            out[1 + b * 4 + i] = (float)c_perm[mini][i];
    }

    // block-reduce sum of per-batch min losses
    float v = minv;
    #pragma unroll
    for (int off = 32; off > 0; off >>= 1)
        v += __shfl_xor(v, off, 64);
    __shared__ float ssum[2];
    const int wave = threadIdx.x >> 6;
    if ((threadIdx.x & 63) == 0) ssum[wave] = v;
    __syncthreads();
    if (threadIdx.x == 0) {
        float s = ssum[0] + ssum[1];
        out[0] = s / (float)B;
    }
}

extern "C" void kernel_launch(void* const* d_in, const int* in_sizes, int n_in,
                              void* d_out, int out_size, void* d_ws, size_t ws_size,
                              hipStream_t stream)
{
    const float* pred   = (const float*)d_in[0];
    const float* target = (const float*)d_in[1];
    const float* mask   = (const float*)d_in[2];
    float* out     = (float*)d_out;
    float* partial = (float*)d_ws;   // NACC * (B*CHUNKS) floats = 86 KB

    const int B = (out_size - 1) / 4;      // out = [loss] + [B,4] perms
    const int T = in_sizes[2] / B;         // mask is [B,T]
    const int nblk = B * CHUNKS;

    pit_partial<<<nblk, TPB, 0, stream>>>(pred, target, mask, partial, T);
    pit_final<<<1, 128, 0, stream>>>(partial, out, B, nblk);
}